// Round 7
// baseline (35.798 us; speedup 1.0000x reference)
//
#include <hip/hip_runtime.h>
#include <cstdint>

// Rule 30, 2 states, r=1, wrap. idx = L + 2C + 4R, table = bits of 30
// reduces to: new = R ^ (C | L).
//
// B=16 rows, W=2048 cells, T=1024 steps, history = T+1 states.
// Output: int32 [B][T+1][W] (reference returns uint8 -> harness int32).
//
// Round-7 = round-6 structure with 2x WRITE CONCURRENCY (A/B discriminator).
//   Round-6 post-mortem: NT stores fixed L2 churn (52->33 us) but we still
//   sustain only 4.0 TB/s vs the fill kernel's 6.7 on the same buffer.
//   Write floor = 134 MB / 6.5 TB/s = 20.7 us. Hypothesis: per-CU
//   outstanding-store depth (4 waves/CU) limits DRAM write efficiency.
//   This round: 2048 single-wave blocks (8 waves/CU), K_STEPS=8, each block
//   expands a 8-step chunk (64 KB slice). Chain redundancy doubles (still
//   compute-trivial); longest chain unchanged (1024 steps). If concurrency
//   is the limiter -> ~25-28 us; if flat -> stream/pipeline theory next.
//
// Structure otherwise proven in rounds 5/6: block (b,r) re-runs row b's
// bit-packed chain from t=0 in registers (ghost-zone window: one 32-bit
// shuffle pair per 8 steps now; rule on the 64-bit window is
// win = (win>>1) ^ (win | (win<<1)); 16-bit halo covers up to 16 steps,
// we use 8 -> valid with margin), parks 8 states in LDS, expands to its
// private output slice with contiguous NT int4 wave-stores.

#define B 16
#define W 2048
#define T_ITERS 1024
#define HIST (T_ITERS + 1)
#define LANES 64
#define K_STEPS 8
#define RBLKS (T_ITERS / K_STEPS)      // 128 chunks
#define ROW_I4 (W / 4)                 // 512 int4 per state row

typedef unsigned long long u64;
typedef int v4i __attribute__((ext_vector_type(4)));

__device__ __forceinline__ void store_nib_nt(v4i* o, unsigned nib) {
    v4i f;
    f.x = (int)(nib & 1u);
    f.y = (int)((nib >> 1) & 1u);
    f.z = (int)((nib >> 2) & 1u);
    f.w = (int)((nib >> 3) & 1u);
    __builtin_nontemporal_store(f, o);   // global_store_dwordx4 ... nt
}

__global__ __launch_bounds__(64) void ca_redundant(const float* __restrict__ x,
                                                   v4i* __restrict__ out) {
    __shared__ unsigned st[K_STEPS][LANES];   // chunk's 8 packed states
    __shared__ unsigned st0[LANES];           // packed t=0 (r==0 only)

    const int blk = blockIdx.x;
    const int b = blk & (B - 1);              // row
    const int r = blk >> 4;                   // time-chunk 0..127
    const int l = threadIdx.x;                // lane, owns cells [32l, 32l+32)

    // ---- pack 32 thresholded floats into a u32 (bit i = cell 32l+i) ----
    const float4* xv = (const float4*)(x + (size_t)b * W + (size_t)l * 32);
    unsigned m = 0;
    #pragma unroll
    for (int i = 0; i < 8; ++i) {
        float4 v = xv[i];
        unsigned n = (v.x >= 0.5f ? 1u : 0u) | (v.y >= 0.5f ? 2u : 0u) |
                     (v.z >= 0.5f ? 4u : 0u) | (v.w >= 0.5f ? 8u : 0u);
        m |= n << (4 * i);
    }
    if (r == 0) st0[l] = m;

    // ---- chain: r+1 exchange groups of 8 steps; save only group r ----
    for (int g = 0; g <= r; ++g) {
        unsigned left  = __shfl(m, (l + LANES - 1) & (LANES - 1));
        unsigned right = __shfl(m, (l + 1) & (LANES - 1));
        // window bit p = cell (32l - 16 + p); bits [16..47] = own cells.
        // 16-bit halo stays valid for 16 steps; we advance only 8.
        u64 win = ((u64)(left >> 16)) | ((u64)m << 16) | ((u64)right << 48);
        if (g < r) {
            #pragma unroll
            for (int j = 0; j < K_STEPS; ++j)
                win = (win >> 1) ^ (win | (win << 1));   // rule 30, 64 bits
            m = (unsigned)(win >> 16);
        } else {
            #pragma unroll
            for (int j = 0; j < K_STEPS; ++j) {
                win = (win >> 1) ^ (win | (win << 1));
                m = (unsigned)(win >> 16);
                st[j][l] = m;                            // 2 lanes/bank: free
            }
        }
    }
    __syncthreads();   // single wave: drains lgkmcnt

    // ---- expand: contiguous NT int4 stores; lane l writes int4 c = l+64i ----
    // nibble c of a packed row lives in word c>>3 = (l>>3)+8i, shift (l&7)*4.
    // LDS reads: 8 lanes broadcast per word, 8 words across 8 banks -> clean.
    if (r == 0) {
        v4i* o = out + ((size_t)b * HIST) * ROW_I4;      // t = 0 row
        #pragma unroll
        for (int i = 0; i < 8; ++i) {
            unsigned u = st0[(l >> 3) + 8 * i];
            store_nib_nt(o + l + 64 * i, (u >> ((l & 7) * 4)) & 0xFu);
        }
    }
    for (int j = 0; j < K_STEPS; ++j) {
        v4i* o = out + ((size_t)b * HIST + (size_t)(r * K_STEPS + 1 + j)) * ROW_I4;
        #pragma unroll
        for (int i = 0; i < 8; ++i) {
            unsigned u = st[j][(l >> 3) + 8 * i];
            store_nib_nt(o + l + 64 * i, (u >> ((l & 7) * 4)) & 0xFu);
        }
    }
}

extern "C" void kernel_launch(void* const* d_in, const int* in_sizes, int n_in,
                              void* d_out, int out_size, void* d_ws, size_t ws_size,
                              hipStream_t stream) {
    const float* x = (const float*)d_in[0];
    // 2048 independent single-wave blocks (8 waves/CU); no workspace needed.
    ca_redundant<<<B * RBLKS, 64, 0, stream>>>(x, (v4i*)d_out);
}

// Round 8
// 29.428 us; speedup vs baseline: 1.2165x; 1.2165x over previous
//
#include <hip/hip_runtime.h>
#include <cstdint>

// Rule 30, 2 states, r=1, wrap. idx = L + 2C + 4R, table = bits of 30
// reduces to: new = R ^ (C | L).
//
// B=16 rows, W=2048 cells, T=1024 steps, history = T+1 states.
// Output: int32 [B][T+1][W] (reference returns uint8 -> harness int32).
//
// Round-8: decouple CHAIN waves from STORE waves.
//   R6: 1 wave/block does chain+expand -> 33.3 us (4.0 TB/s, floor 20.7).
//   R7: 2x single-wave blocks -> 35.8 us: more waves but each also runs a
//       redundant chain; store-dedicated issue didn't increase. Refuted.
//   R8: 1024 blocks x 256 threads. Wave 0 re-runs row b's bit-packed chain
//       from t=0 (ghost-zone window, 1 shuffle pair / 16 steps,
//       win = (win>>1) ^ (win | (win<<1))), parks its 16-state chunk in LDS.
//       Barrier. ALL FOUR waves expand 4 states each with NT int4 stores.
//       Chain work per CU unchanged vs R6 (4 chains/CU = 1/SIMD ~ 5 us);
//       store-issue waves per CU: 4 -> 16. If store-issue-bound -> ~24-26 us.

#define B 16
#define W 2048
#define T_ITERS 1024
#define HIST (T_ITERS + 1)
#define LANES 64
#define K_STEPS 16
#define RBLKS (T_ITERS / K_STEPS)      // 64 chunks
#define ROW_I4 (W / 4)                 // 512 int4 per state row

typedef unsigned long long u64;
typedef int v4i __attribute__((ext_vector_type(4)));

__device__ __forceinline__ void store_nib_nt(v4i* o, unsigned nib) {
    v4i f;
    f.x = (int)(nib & 1u);
    f.y = (int)((nib >> 1) & 1u);
    f.z = (int)((nib >> 2) & 1u);
    f.w = (int)((nib >> 3) & 1u);
    __builtin_nontemporal_store(f, o);   // global_store_dwordx4 ... nt
}

__global__ __launch_bounds__(256) void ca_redundant(const float* __restrict__ x,
                                                    v4i* __restrict__ out) {
    __shared__ unsigned st[K_STEPS][LANES];   // chunk's 16 packed states
    __shared__ unsigned st0[LANES];           // packed t=0 (r==0 only)

    const int blk = blockIdx.x;
    const int b = blk & (B - 1);              // row
    const int r = blk >> 4;                   // time-chunk 0..63
    const int tid = threadIdx.x;
    const int wave = tid >> 6;                // 0..3
    const int l = tid & 63;                   // lane

    if (wave == 0) {
        // ---- pack 32 thresholded floats into a u32 (bit i = cell 32l+i) ----
        const float4* xv = (const float4*)(x + (size_t)b * W + (size_t)l * 32);
        unsigned m = 0;
        #pragma unroll
        for (int i = 0; i < 8; ++i) {
            float4 v = xv[i];
            unsigned n = (v.x >= 0.5f ? 1u : 0u) | (v.y >= 0.5f ? 2u : 0u) |
                         (v.z >= 0.5f ? 4u : 0u) | (v.w >= 0.5f ? 8u : 0u);
            m |= n << (4 * i);
        }
        if (r == 0) st0[l] = m;

        // ---- chain: r+1 exchange groups of 16 steps; save only group r ----
        for (int g = 0; g <= r; ++g) {
            unsigned left  = __shfl(m, (l + LANES - 1) & (LANES - 1));
            unsigned right = __shfl(m, (l + 1) & (LANES - 1));
            // window bit p = cell (32l - 16 + p); bits [16..47] = own cells
            u64 win = ((u64)(left >> 16)) | ((u64)m << 16) | ((u64)right << 48);
            if (g < r) {
                #pragma unroll
                for (int j = 0; j < K_STEPS; ++j)
                    win = (win >> 1) ^ (win | (win << 1));   // rule 30, 64 bits
                m = (unsigned)(win >> 16);                   // valid at 16 steps
            } else {
                #pragma unroll
                for (int j = 0; j < K_STEPS; ++j) {
                    win = (win >> 1) ^ (win | (win << 1));
                    m = (unsigned)(win >> 16);               // valid for j<=15
                    st[j][l] = m;                            // 2 lanes/bank: free
                }
            }
        }
    }
    __syncthreads();

    // ---- expand: all 4 waves, 4 states each; contiguous NT int4 stores ----
    // nibble c of a packed row: word c>>3 = (l>>3)+8i, shift (l&7)*4.
    // LDS reads: 8-lane broadcast per word, 8 words across 8 banks -> clean.
    if (r == 0) {
        // t = 0 row: 512 int4 split across all 256 threads (2 each)
        v4i* o = out + ((size_t)b * HIST) * ROW_I4;
        #pragma unroll
        for (int h = 0; h < 2; ++h) {
            int c = tid + 256 * h;
            unsigned u = st0[c >> 3];
            store_nib_nt(o + c, (u >> ((c & 7) * 4)) & 0xFu);
        }
    }
    #pragma unroll
    for (int jj = 0; jj < 4; ++jj) {
        const int j = wave * 4 + jj;
        v4i* o = out + ((size_t)b * HIST + (size_t)(r * K_STEPS + 1 + j)) * ROW_I4;
        #pragma unroll
        for (int i = 0; i < 8; ++i) {
            unsigned u = st[j][(l >> 3) + 8 * i];
            store_nib_nt(o + l + 64 * i, (u >> ((l & 7) * 4)) & 0xFu);
        }
    }
}

extern "C" void kernel_launch(void* const* d_in, const int* in_sizes, int n_in,
                              void* d_out, int out_size, void* d_ws, size_t ws_size,
                              hipStream_t stream) {
    const float* x = (const float*)d_in[0];
    // 1024 independent blocks (4 waves each); no workspace needed.
    ca_redundant<<<B * RBLKS, 256, 0, stream>>>(x, (v4i*)d_out);
}